// Round 8
// baseline (360.676 us; speedup 1.0000x reference)
//
#include <hip/hip_runtime.h>
#include <hip/hip_bf16.h>
#include <stdint.h>

typedef __attribute__((ext_vector_type(8))) short bf16x8;
typedef __attribute__((ext_vector_type(4))) short bf16x4;
typedef __attribute__((ext_vector_type(4))) float f32x4;

__device__ __forceinline__ float b2f(short s) {
  union { unsigned u; float f; } cv;
  cv.u = ((unsigned)(unsigned short)s) << 16;
  return cv.f;
}
__device__ __forceinline__ short f2b(float f) {
  __hip_bfloat16 h = __float2bfloat16(f);
  return *reinterpret_cast<short*>(&h);
}
__device__ __forceinline__ void ldsdma16(const short* g, short* l) {
  __builtin_amdgcn_global_load_lds((const __attribute__((address_space(1))) unsigned int*)g,
                                   (__attribute__((address_space(3))) unsigned int*)l, 16, 0, 0);
}

// Layouts:
//  xT[b][t][c] bf16 (c contiguous, 512/row), per-level elem offsets {0, 8388608, 12582912}.
//  W frags (k-major r = k*512+c): fid = mb*48+kt, lane l: o = mb*16+(l&15), r = kt*32+(l>>4)*8+j.
//  owF1 frags (j-major rr = j*512+c): fid = kt (0..47), lane l: k = l&15 (rows>=3 zero),
//    rr = kt*32+(l>>4)*8+j; stored twice: hi = bf16(v), lo = bf16(v - hi).

// ---------- fused prep: setup (W frags, owF1, mask) + transpose + layer-1 offset-conv ----------
// grid (448, 4). Setup work distributed as 4 strided chunks over all 458752 threads.
__global__ __launch_bounds__(256) void prep_kernel(
    const float* __restrict__ x0p, const float* __restrict__ x1p, const float* __restrict__ x2p,
    const float* __restrict__ ow, float* __restrict__ P, __hip_bfloat16* __restrict__ xT,
    const float* __restrict__ w0, const float* __restrict__ w1,
    __hip_bfloat16* __restrict__ d0, __hip_bfloat16* __restrict__ d1,
    const float* __restrict__ ow1,
    __hip_bfloat16* __restrict__ of1hi, __hip_bfloat16* __restrict__ of1lo,
    const float* __restrict__ m0, const float* __restrict__ m1, const float* __restrict__ m2,
    float* __restrict__ mo) {
  __shared__ float tile[128][66];  // [c][t]; col 64 = t-1 halo, col 65 = t+64 halo
  __shared__ float red[3][4][64];
  int tid = threadIdx.x, lane = tid & 63, w = tid >> 6;

  // ---- setup chunk (former setup_kernel), 4 items per thread, r-strided for coalescing ----
  {
    int gid = (blockIdx.y * 448 + blockIdx.x) * 256 + tid;
#pragma unroll
    for (int r = 0; r < 4; ++r) {
      int i = r * 458752 + gid;
      if (i < 1572864) {
        int l = i >= 786432;
        int i2 = i - (l ? 786432 : 0);
        const float* wsrc = l ? w1 : w0;
        __hip_bfloat16* d = l ? d1 : d0;
        int fid = i2 >> 9, within = i2 & 511, ln = within >> 3, j = within & 7;
        int mb = fid / 48, kt = fid - mb * 48;
        int o = mb * 16 + (ln & 15);
        int rr = kt * 32 + (ln >> 4) * 8 + j;
        int k = rr >> 9, c = rr & 511;
        d[i2] = __float2bfloat16(wsrc[o * 1536 + c * 3 + k]);
      } else if (i < 1597440) {
        int i4 = i - 1572864;
        int fid = i4 >> 9, within = i4 & 511, ln = within >> 3, jj = within & 7;
        int o = ln & 15;
        int rr = fid * 32 + (ln >> 4) * 8 + jj;
        int j = rr >> 9, c = rr & 511;
        float v = (o < 3) ? ow1[o * 1536 + c * 3 + j] : 0.f;
        __hip_bfloat16 hi = __float2bfloat16(v);
        of1hi[i4] = hi;
        of1lo[i4] = __float2bfloat16(v - __bfloat162float(hi));
      } else {
        int i2 = i - 1597440;
        if (i2 < 28672) {
          float v;
          if (i2 < 16384) v = m0[i2];
          else if (i2 < 24576) v = m1[i2 - 16384];
          else v = m2[i2 - 24576];
          mo[i2] = (v != 0.f) ? 1.f : 0.f;
        }
      }
    }
  }

  // ---- transpose + offconv1 (unchanged from r7 prep) ----
  int bx = blockIdx.x;
  int lv = (bx < 256) ? 0 : ((bx < 384) ? 1 : 2);
  int lbx = bx - ((lv == 0) ? 0 : ((lv == 1) ? 256 : 384));
  int tsh = 11 - lv;
  int T = 1 << tsh;
  const float* x = (lv == 0) ? x0p : ((lv == 1) ? x1p : x2p);
  float* Pl = P + ((lv == 0) ? 0 : ((lv == 1) ? 196608 : 294912));
  __hip_bfloat16* xo = xT + ((lv == 0) ? 0 : ((lv == 1) ? 8388608 : 12582912));
  int nchunk = T >> 6;
  int b = lbx >> (tsh - 6);
  int tb = (lbx & (nchunk - 1)) << 6;
  int c0g = blockIdx.y * 128;
  const float* xb = x + ((size_t)(b * 512 + c0g) << tsh);
  for (int idx = tid; idx < 2048; idx += 256) {
    int c = idx >> 4, tq = idx & 15;
    f32x4 v = *(const f32x4*)(xb + ((size_t)c << tsh) + tb + (tq << 2));
#pragma unroll
    for (int j = 0; j < 4; ++j) tile[c][(tq << 2) + j] = v[j];
  }
  if (tid < 128) {
    int c = tid;
    tile[c][64] = (tb > 0) ? xb[((size_t)c << tsh) + tb - 1] : 0.f;
  } else {
    int c = tid - 128;
    tile[c][65] = (tb + 64 < T) ? xb[((size_t)c << tsh) + tb + 64] : 0.f;
  }
  __syncthreads();

  {
    int tl2 = tid >> 2, cq = tid & 3;
    short* orow = (short*)xo + (((size_t)(b << tsh) + tb + tl2) << 9) + c0g;
#pragma unroll
    for (int h = 0; h < 4; ++h) {
      int cb = cq * 8 + h * 32;
      bf16x8 v;
#pragma unroll
      for (int j = 0; j < 8; ++j) v[j] = f2b(tile[cb + j][tl2]);
      *(bf16x8*)(orow + cb) = v;
    }
  }

  int im = (lane == 0) ? 64 : lane - 1;
  int ip = (lane == 63) ? 65 : lane + 1;
  float a0 = 0.f, a1 = 0.f, a2 = 0.f;
  for (int c = 0; c < 32; ++c) {
    int cc = w * 32 + c;
    float xm = tile[cc][im];
    float x0 = tile[cc][lane];
    float xp = tile[cc][ip];
    const float* wp = ow + (c0g + cc) * 3;
    a0 += wp[0] * xm + wp[1] * x0 + wp[2] * xp;
    a1 += wp[1536] * xm + wp[1537] * x0 + wp[1538] * xp;
    a2 += wp[3072] * xm + wp[3073] * x0 + wp[3074] * xp;
  }
  red[0][w][lane] = a0;
  red[1][w][lane] = a1;
  red[2][w][lane] = a2;
  __syncthreads();
  if (w < 3) {
    float s = red[w][0][lane] + red[w][1][lane] + red[w][2][lane] + red[w][3][lane];
    Pl[blockIdx.y * (24 << tsh) + ((b * 3 + w) << tsh) + tb + lane] = s;
  }
}

// ---------- layer-2 offset conv: skinny MFMA on x1T, ow in hi/lo bf16 ----------
__global__ __launch_bounds__(256, 4) void offconv2_kernel(const __hip_bfloat16* __restrict__ xT,
                                                          const __hip_bfloat16* __restrict__ oHi,
                                                          const __hip_bfloat16* __restrict__ oLo,
                                                          float* __restrict__ offc) {
  int tid = threadIdx.x, lane = tid & 63, wid = tid >> 6;
  int nt = blockIdx.x * 4 + wid;
  int lv = (nt < 1024) ? 0 : ((nt < 1536) ? 1 : 2);
  int ntl = nt - ((lv == 0) ? 0 : ((lv == 1) ? 1024 : 1536));
  int tsh = 11 - lv;
  int T = 1 << tsh;
  const short* xp = (const short*)xT + ((lv == 0) ? 0 : ((lv == 1) ? 8388608 : 12582912));
  float* oc = offc + ((lv == 0) ? 0 : ((lv == 1) ? 49152 : 73728));
  int n = (ntl << 4) + (lane & 15);
  int b = n >> tsh;
  int t = n & (T - 1);
  const short* hip_ = (const short*)oHi + lane * 8;
  const short* lop_ = (const short*)oLo + lane * 8;
  int co = (lane >> 4) << 3;
  f32x4 acc = {};
  for (int kt = 0; kt < 48; ++kt) {
    int j = kt >> 4;
    int c0 = ((kt & 15) << 5) + co;
    int row = t + j - 1;
    bf16x8 bv = {};
    if ((unsigned)row < (unsigned)T)
      bv = *(const bf16x8*)(xp + (((size_t)(b << tsh) + row) << 9) + c0);
    bf16x8 ah = *(const bf16x8*)(hip_ + ((size_t)kt << 9));
    bf16x8 al = *(const bf16x8*)(lop_ + ((size_t)kt << 9));
    acc = __builtin_amdgcn_mfma_f32_16x16x32_bf16(ah, bv, acc, 0, 0, 0);
    acc = __builtin_amdgcn_mfma_f32_16x16x32_bf16(al, bv, acc, 0, 0, 0);
  }
  if ((lane >> 4) == 0) {
#pragma unroll
    for (int r = 0; r < 3; ++r) oc[((b * 3 + r) << tsh) + t] = acc[r];
  }
}

// ---------- fused deform-GEMM: BK=64 (24 phases), W via LDS-DMA (wave-private kh-parity
// dbuf), counted vmcnt (never 0 in-loop), same-phase gather->lerp with full-phase cover ----------
// grid (224, 2): 128-t strip x m-half (256 rows), 4 waves m-split, acc[4][8] (128 AGPR).
// Phase p: [G(p+1) x8] vmcnt(12) [W/S kh0 reads, 32 MFMA] [DMA W(2p+2)] vmcnt(12)
//          [kh1 block] [DMA W(2p+3)] [lerp->S(p+1) (auto vmcnt(8))] lgkm(0) barrier.
template <bool LAYER2, bool OUT_BF16>
__global__ __launch_bounds__(256, 2) void dgemm_kernel(
    const __hip_bfloat16* __restrict__ xT, const __hip_bfloat16* __restrict__ Wf,
    const float* __restrict__ off0, const float* __restrict__ off1,
    const float* __restrict__ off2, const float* __restrict__ P1,
    const float* __restrict__ offc2, const float* __restrict__ ob0v,
    const float* __restrict__ ob1v, const float* __restrict__ bias,
    const float* __restrict__ mk0, const float* __restrict__ mk1, const float* __restrict__ mk2,
    void* __restrict__ o0, void* __restrict__ o1, void* __restrict__ o2) {
  __shared__ short sS[2][8192];       // S dbuf: [buf][(t-chunk j)*1024 + kh*512 + slot]
  __shared__ short wbuf[2][4][2048];  // W: [kh-parity][wave][4 frags x 512]
  __shared__ int s_q[3][128];
  __shared__ float s_w0[3][128];
  __shared__ float s_w1[3][128];
  int tid = threadIdx.x, lane = tid & 63, wid = tid >> 6;
  int bx = blockIdx.x;
  int lv = (bx < 128) ? 0 : ((bx < 192) ? 1 : 2);
  int lbx = bx - ((lv == 0) ? 0 : ((lv == 1) ? 128 : 192));
  int tsh = 11 - lv;
  int T = 1 << tsh;
  const short* xp = (const short*)xT + ((lv == 0) ? 0 : ((lv == 1) ? 8388608 : 12582912));
  const float* offin = (lv == 0) ? off0 : ((lv == 1) ? off1 : off2);
  const float* P1l = P1 + ((lv == 0) ? 0 : ((lv == 1) ? 196608 : 294912));
  const float* oc2 = offc2 + ((lv == 0) ? 0 : ((lv == 1) ? 49152 : 73728));
  const float* mask = (lv == 0) ? mk0 : ((lv == 1) ? mk1 : mk2);
  void* outp = (lv == 0) ? o0 : ((lv == 1) ? o1 : o2);
  int nchunk = T >> 7;
  int b = lbx >> (tsh - 7);
  int tb = (lbx & (nchunk - 1)) << 7;
  int mhalf = blockIdx.y;

  // per-(tap,t) sample params: clamped rows + zeroable weights
  for (int idx = tid; idx < 384; idx += 256) {
    int k = idx >> 7, tl = idx & 127, t = tb + tl;
    int oi = ((b * 3 + k) << tsh) + t;
    int PT = 24 << tsh;
    float o = offin[oi] + ob0v[k];
    o += P1l[oi] + P1l[PT + oi] + P1l[2 * PT + oi] + P1l[3 * PT + oi];
    if (LAYER2) o += ob1v[k] + oc2[oi];
    float pos = (float)(t + k - 1) + o;
    float pf = floorf(pos);
    float fr = pos - pf;
    int q0 = (int)pf;
    int q1 = q0 + 1;
    bool ok0 = (unsigned)q0 < (unsigned)T;
    bool ok1 = (unsigned)q1 < (unsigned)T;
    int q0c = min(max(q0, 0), T - 1);
    int q1c = min(max(q1, 0), T - 1);
    s_q[k][tl] = (q0c & 0xffff) | (q1c << 16);
    s_w0[k][tl] = ok0 ? (1.f - fr) : 0.f;
    s_w1[k][tl] = ok1 ? fr : 0.f;
  }
  __syncthreads();

  int tlh0 = wid * 16 + (lane & 15);
  int tlh1 = 64 + wid * 16 + (lane & 15);
  int aq0[2], aq1[2];
  float aw0[2], aw1[2];
#define LOADTAP(K)                                   \
  {                                                  \
    int qp0 = s_q[K][tlh0], qp1 = s_q[K][tlh1];      \
    aq0[0] = qp0 & 0xffff; aq1[0] = (qp0 >> 16);     \
    aq0[1] = qp1 & 0xffff; aq1[1] = (qp1 >> 16);     \
    aw0[0] = s_w0[K][tlh0]; aw1[0] = s_w1[K][tlh0];  \
    aw0[1] = s_w0[K][tlh1]; aw1[1] = s_w1[K][tlh1];  \
  }
  LOADTAP(0)

  f32x4 acc[4][8] = {};
  const short* wfp = (const short*)Wf + (size_t)(mhalf * 16 + wid * 4) * 48 * 512 + lane * 8;
  unsigned co = (unsigned)((lane >> 4) << 3);
  const short* xrow = xp + (((size_t)(b << tsh)) << 9);
  short* smy = &sS[0][0] + (wid << 10) + lane * 8;   // +h*4096 +kh*512 +buf*8192
  const short* smrd = &sS[0][0] + lane * 8;          // +buf*8192 +jj*1024 +kh*512
  short* wbase = &wbuf[0][0][0] + (wid << 11);       // wave-uniform DMA dest; +par*8192 +i*512
  const short* wrd = &wbuf[0][0][0] + (wid << 11) + lane * 8;

  bf16x8 gq0[2][2], gq1[2][2];  // [kh][h]

#define GISSUE(PN)                                                        \
  {                                                                       \
    unsigned cb_ = ((unsigned)((2 * (PN)) & 15)) << 5;                    \
    _Pragma("unroll") for (int h = 0; h < 2; ++h) {                       \
      unsigned r0_ = ((unsigned)aq0[h]) << 9;                             \
      unsigned r1_ = ((unsigned)aq1[h]) << 9;                             \
      gq0[0][h] = *(const bf16x8*)(xrow + r0_ + cb_ + co);                \
      gq1[0][h] = *(const bf16x8*)(xrow + r1_ + cb_ + co);                \
      gq0[1][h] = *(const bf16x8*)(xrow + r0_ + cb_ + 32 + co);           \
      gq1[1][h] = *(const bf16x8*)(xrow + r1_ + cb_ + 32 + co);           \
    }                                                                     \
  }
#define WDMA(S, PAR)                                                      \
  {                                                                       \
    _Pragma("unroll") for (int i = 0; i < 4; ++i)                         \
        ldsdma16(wfp + ((size_t)(i * 48 + (S)) << 9),                     \
                 wbase + ((PAR) << 13) + (i << 9));                       \
  }
#define SLERP(PN)                                                         \
  {                                                                       \
    short* smw_ = smy + (((PN) & 1) << 13);                               \
    _Pragma("unroll") for (int kh = 0; kh < 2; ++kh)                      \
    _Pragma("unroll") for (int h = 0; h < 2; ++h) {                       \
      bf16x8 ov;                                                          \
      _Pragma("unroll") for (int j = 0; j < 8; ++j)                       \
        ov[j] = f2b(b2f(gq0[kh][h][j]) * aw0[h] +                         \
                    b2f(gq1[kh][h][j]) * aw1[h]);                         \
      *(bf16x8*)(smw_ + (h << 12) + (kh << 9)) = ov;                      \
    }                                                                     \
  }
#define KHBLOCK(PAR, KH, BUF)                                             \
  {                                                                       \
    bf16x8 Af_[4];                                                        \
    _Pragma("unroll") for (int i = 0; i < 4; ++i)                         \
        Af_[i] = *(const bf16x8*)(wrd + ((PAR) << 13) + (i << 9));        \
    bf16x8 bv_[8];                                                        \
    _Pragma("unroll") for (int jj = 0; jj < 8; ++jj)                      \
        bv_[jj] = *(const bf16x8*)(smrd + ((BUF) << 13) + (jj << 10) +    \
                                   ((KH) << 9));                          \
    __builtin_amdgcn_s_setprio(1);                                        \
    _Pragma("unroll") for (int i = 0; i < 4; ++i)                         \
    _Pragma("unroll") for (int jj = 0; jj < 8; ++jj)                      \
        acc[i][jj] = __builtin_amdgcn_mfma_f32_16x16x32_bf16(             \
            Af_[i], bv_[jj], acc[i][jj], 0, 0, 0);                        \
    __builtin_amdgcn_s_setprio(0);                                        \
  }

  // ---- prologue: G(0), DMA W(0)/W(1), lerp->S(0) buf0 ----
  GISSUE(0)
  WDMA(0, 0)
  WDMA(1, 1)
  SLERP(0)
  asm volatile("s_waitcnt lgkmcnt(0)" ::: "memory");
  __builtin_amdgcn_s_barrier();
  asm volatile("" ::: "memory");

#pragma unroll 1
  for (int p = 0; p < 23; ++p) {
    if (p == 7) LOADTAP(1)
    else if (p == 15) LOADTAP(2)
    GISSUE(p + 1)
    asm volatile("s_waitcnt vmcnt(12)" ::: "memory");  // W(2p) landed
    int buf = p & 1;
    KHBLOCK(0, 0, buf)
    asm volatile("" ::: "memory");  // keep DMA issue below the par0 reads
    WDMA(2 * p + 2, 0)
    asm volatile("s_waitcnt vmcnt(12)" ::: "memory");  // W(2p+1) landed
    KHBLOCK(1, 1, buf)
    asm volatile("" ::: "memory");
    WDMA(2 * p + 3, 1)
    SLERP(p + 1)  // compiler emits vmcnt(8): drains gathers, keeps new DMAs
    asm volatile("s_waitcnt lgkmcnt(0)" ::: "memory");
    __builtin_amdgcn_s_barrier();
    asm volatile("" ::: "memory");
  }
  // ---- peeled last phase p=23 (S in buf1, W 46/47) ----
  asm volatile("s_waitcnt vmcnt(4)" ::: "memory");
  KHBLOCK(0, 0, 1)
  asm volatile("s_waitcnt vmcnt(0)" ::: "memory");
  KHBLOCK(1, 1, 1)
#undef KHBLOCK
#undef SLERP
#undef WDMA
#undef GISSUE
#undef LOADTAP

  // epilogue: D row = (lane>>4)*4 + reg (m), col = lane&15 (t); 8 t-tiles
  int lrow = lane & 15, lq = lane >> 4;
  int mbase = mhalf * 256 + wid * 64;
  float bvals[4][4];
#pragma unroll
  for (int i = 0; i < 4; ++i)
#pragma unroll
    for (int r = 0; r < 4; ++r) bvals[i][r] = bias[mbase + i * 16 + lq * 4 + r];
#pragma unroll
  for (int j = 0; j < 8; ++j) {
    int col = j * 16 + lrow;
    int t = tb + col;
    float mk = mask[(b << tsh) + t];
    if (OUT_BF16) {
      short* orow = (short*)outp + (((size_t)(b << tsh) + t) << 9);
#pragma unroll
      for (int i = 0; i < 4; ++i) {
        bf16x4 pv;
#pragma unroll
        for (int r = 0; r < 4; ++r)
          pv[r] = f2b(fmaxf(acc[i][j][r] + bvals[i][r], 0.f) * mk);
        *(bf16x4*)(orow + mbase + i * 16 + lq * 4) = pv;
      }
    } else {
#pragma unroll
      for (int i = 0; i < 4; ++i) {
        int m = mbase + i * 16 + lq * 4;
#pragma unroll
        for (int r = 0; r < 4; ++r) {
          float v = fmaxf(acc[i][j][r] + bvals[i][r], 0.f) * mk;
          ((float*)outp)[(((size_t)(b * 512 + m + r)) << tsh) + t] = v;
        }
      }
    }
  }
}

// ---------- launch ----------
extern "C" void kernel_launch(void* const* d_in, const int* in_sizes, int n_in, void* d_out,
                              int out_size, void* d_ws, size_t ws_size, hipStream_t stream) {
  const float* feats[3] = {(const float*)d_in[0], (const float*)d_in[3], (const float*)d_in[6]};
  const float* maskp[3] = {(const float*)d_in[1], (const float*)d_in[4], (const float*)d_in[7]};
  const float* offs[3] = {(const float*)d_in[2], (const float*)d_in[5], (const float*)d_in[8]};
  const float* w[2] = {(const float*)d_in[9], (const float*)d_in[13]};
  const float* bias[2] = {(const float*)d_in[10], (const float*)d_in[14]};
  const float* ow[2] = {(const float*)d_in[11], (const float*)d_in[15]};
  const float* ob[2] = {(const float*)d_in[12], (const float*)d_in[16]};

  const size_t YOFF[3] = {0, 8388608, 12582912};
  const size_t MOFF = 14680064;

  uint8_t* ws = (uint8_t*)d_ws;
  __hip_bfloat16* Wf0 = (__hip_bfloat16*)ws;                 // 1,572,864 B
  __hip_bfloat16* Wf1 = (__hip_bfloat16*)(ws + 1572864);     // 1,572,864 B
  __hip_bfloat16* owF1hi = (__hip_bfloat16*)(ws + 3145728);  // 49,152 B
  __hip_bfloat16* owF1lo = (__hip_bfloat16*)(ws + 3194880);  // 49,152 B
  float* P1 = (float*)(ws + 3244032);                        // 1,376,256 B
  float* offc2 = (float*)(ws + 4620288);                     // 344,064 B
  __hip_bfloat16* fT = (__hip_bfloat16*)(ws + 8388608);      // 29,360,128 B
  __hip_bfloat16* x1T = (__hip_bfloat16*)(ws + 37748736);    // 29,360,128 B (end 67,108,864)

  float* outf = (float*)d_out;

  // fused setup + transpose + layer-1 offset conv (reads feats once, one launch fewer)
  prep_kernel<<<dim3(448, 4), 256, 0, stream>>>(
      feats[0], feats[1], feats[2], ow[0], P1, fT, w[0], w[1], Wf0, Wf1, ow[1], owF1hi, owF1lo,
      maskp[0], maskp[1], maskp[2], outf + MOFF);

  // layer 1
  dgemm_kernel<false, true><<<dim3(224, 2), 256, 0, stream>>>(
      fT, Wf0, offs[0], offs[1], offs[2], P1, offc2, ob[0], ob[1], bias[0],
      maskp[0], maskp[1], maskp[2], (void*)x1T, (void*)(x1T + YOFF[1]), (void*)(x1T + YOFF[2]));

  // layer 2
  offconv2_kernel<<<448, 256, 0, stream>>>(x1T, owF1hi, owF1lo, offc2);
  dgemm_kernel<true, false><<<dim3(224, 2), 256, 0, stream>>>(
      x1T, Wf1, offs[0], offs[1], offs[2], P1, offc2, ob[0], ob[1], bias[1],
      maskp[0], maskp[1], maskp[2], (void*)(outf + YOFF[0]), (void*)(outf + YOFF[1]),
      (void*)(outf + YOFF[2]));
}

// Round 9
// 322.791 us; speedup vs baseline: 1.1174x; 1.1174x over previous
//
#include <hip/hip_runtime.h>
#include <hip/hip_bf16.h>
#include <stdint.h>

typedef __attribute__((ext_vector_type(8))) short bf16x8;
typedef __attribute__((ext_vector_type(4))) short bf16x4;
typedef __attribute__((ext_vector_type(4))) float f32x4;

__device__ __forceinline__ float b2f(short s) {
  union { unsigned u; float f; } cv;
  cv.u = ((unsigned)(unsigned short)s) << 16;
  return cv.f;
}
__device__ __forceinline__ short f2b(float f) {
  __hip_bfloat16 h = __float2bfloat16(f);
  return *reinterpret_cast<short*>(&h);
}

// Layouts:
//  xT[b][t][c] bf16 (c contiguous, 512/row), per-level elem offsets {0, 8388608, 12582912}.
//  W frags (k-major r = k*512+c): fid = mb*48+kt, lane l: o = mb*16+(l&15), r = kt*32+(l>>4)*8+j.
//  owF1 frags (j-major rr = j*512+c): fid = kt (0..47), lane l: k = l&15 (rows>=3 zero),
//    rr = kt*32+(l>>4)*8+j; stored twice: hi = bf16(v), lo = bf16(v - hi).

// ---------- fused prep: setup (W frags, owF1, mask) + transpose + layer-1 offset-conv ----------
// grid (448, 4). Setup work distributed as 4 strided chunks over all 458752 threads.
__global__ __launch_bounds__(256) void prep_kernel(
    const float* __restrict__ x0p, const float* __restrict__ x1p, const float* __restrict__ x2p,
    const float* __restrict__ ow, float* __restrict__ P, __hip_bfloat16* __restrict__ xT,
    const float* __restrict__ w0, const float* __restrict__ w1,
    __hip_bfloat16* __restrict__ d0, __hip_bfloat16* __restrict__ d1,
    const float* __restrict__ ow1,
    __hip_bfloat16* __restrict__ of1hi, __hip_bfloat16* __restrict__ of1lo,
    const float* __restrict__ m0, const float* __restrict__ m1, const float* __restrict__ m2,
    float* __restrict__ mo) {
  __shared__ float tile[128][66];  // [c][t]; col 64 = t-1 halo, col 65 = t+64 halo
  __shared__ float red[3][4][64];
  int tid = threadIdx.x, lane = tid & 63, w = tid >> 6;

  // ---- setup chunk (former setup_kernel), 4 items per thread, r-strided for coalescing ----
  {
    int gid = (blockIdx.y * 448 + blockIdx.x) * 256 + tid;
#pragma unroll
    for (int r = 0; r < 4; ++r) {
      int i = r * 458752 + gid;
      if (i < 1572864) {
        int l = i >= 786432;
        int i2 = i - (l ? 786432 : 0);
        const float* wsrc = l ? w1 : w0;
        __hip_bfloat16* d = l ? d1 : d0;
        int fid = i2 >> 9, within = i2 & 511, ln = within >> 3, j = within & 7;
        int mb = fid / 48, kt = fid - mb * 48;
        int o = mb * 16 + (ln & 15);
        int rr = kt * 32 + (ln >> 4) * 8 + j;
        int k = rr >> 9, c = rr & 511;
        d[i2] = __float2bfloat16(wsrc[o * 1536 + c * 3 + k]);
      } else if (i < 1597440) {
        int i4 = i - 1572864;
        int fid = i4 >> 9, within = i4 & 511, ln = within >> 3, jj = within & 7;
        int o = ln & 15;
        int rr = fid * 32 + (ln >> 4) * 8 + jj;
        int j = rr >> 9, c = rr & 511;
        float v = (o < 3) ? ow1[o * 1536 + c * 3 + j] : 0.f;
        __hip_bfloat16 hi = __float2bfloat16(v);
        of1hi[i4] = hi;
        of1lo[i4] = __float2bfloat16(v - __bfloat162float(hi));
      } else {
        int i2 = i - 1597440;
        if (i2 < 28672) {
          float v;
          if (i2 < 16384) v = m0[i2];
          else if (i2 < 24576) v = m1[i2 - 16384];
          else v = m2[i2 - 24576];
          mo[i2] = (v != 0.f) ? 1.f : 0.f;
        }
      }
    }
  }

  // ---- transpose + offconv1 ----
  int bx = blockIdx.x;
  int lv = (bx < 256) ? 0 : ((bx < 384) ? 1 : 2);
  int lbx = bx - ((lv == 0) ? 0 : ((lv == 1) ? 256 : 384));
  int tsh = 11 - lv;
  int T = 1 << tsh;
  const float* x = (lv == 0) ? x0p : ((lv == 1) ? x1p : x2p);
  float* Pl = P + ((lv == 0) ? 0 : ((lv == 1) ? 196608 : 294912));
  __hip_bfloat16* xo = xT + ((lv == 0) ? 0 : ((lv == 1) ? 8388608 : 12582912));
  int nchunk = T >> 6;
  int b = lbx >> (tsh - 6);
  int tb = (lbx & (nchunk - 1)) << 6;
  int c0g = blockIdx.y * 128;
  const float* xb = x + ((size_t)(b * 512 + c0g) << tsh);
  for (int idx = tid; idx < 2048; idx += 256) {
    int c = idx >> 4, tq = idx & 15;
    f32x4 v = *(const f32x4*)(xb + ((size_t)c << tsh) + tb + (tq << 2));
#pragma unroll
    for (int j = 0; j < 4; ++j) tile[c][(tq << 2) + j] = v[j];
  }
  if (tid < 128) {
    int c = tid;
    tile[c][64] = (tb > 0) ? xb[((size_t)c << tsh) + tb - 1] : 0.f;
  } else {
    int c = tid - 128;
    tile[c][65] = (tb + 64 < T) ? xb[((size_t)c << tsh) + tb + 64] : 0.f;
  }
  __syncthreads();

  {
    int tl2 = tid >> 2, cq = tid & 3;
    short* orow = (short*)xo + (((size_t)(b << tsh) + tb + tl2) << 9) + c0g;
#pragma unroll
    for (int h = 0; h < 4; ++h) {
      int cb = cq * 8 + h * 32;
      bf16x8 v;
#pragma unroll
      for (int j = 0; j < 8; ++j) v[j] = f2b(tile[cb + j][tl2]);
      *(bf16x8*)(orow + cb) = v;
    }
  }

  int im = (lane == 0) ? 64 : lane - 1;
  int ip = (lane == 63) ? 65 : lane + 1;
  float a0 = 0.f, a1 = 0.f, a2 = 0.f;
  for (int c = 0; c < 32; ++c) {
    int cc = w * 32 + c;
    float xm = tile[cc][im];
    float x0 = tile[cc][lane];
    float xp = tile[cc][ip];
    const float* wp = ow + (c0g + cc) * 3;
    a0 += wp[0] * xm + wp[1] * x0 + wp[2] * xp;
    a1 += wp[1536] * xm + wp[1537] * x0 + wp[1538] * xp;
    a2 += wp[3072] * xm + wp[3073] * x0 + wp[3074] * xp;
  }
  red[0][w][lane] = a0;
  red[1][w][lane] = a1;
  red[2][w][lane] = a2;
  __syncthreads();
  if (w < 3) {
    float s = red[w][0][lane] + red[w][1][lane] + red[w][2][lane] + red[w][3][lane];
    Pl[blockIdx.y * (24 << tsh) + ((b * 3 + w) << tsh) + tb + lane] = s;
  }
}

// ---------- layer-2 offset conv: skinny MFMA on x1T, 2-way k-split + LDS reduce ----------
// grid 896 blocks x 4 waves: wave = (tile slot 0/1, khalf 0/1). Each wave does 24 of the
// 48 kt iterations (halves the serial load->MFMA chain); khalf partials combined via LDS.
__global__ __launch_bounds__(256, 4) void offconv2_kernel(const __hip_bfloat16* __restrict__ xT,
                                                          const __hip_bfloat16* __restrict__ oHi,
                                                          const __hip_bfloat16* __restrict__ oLo,
                                                          float* __restrict__ offc) {
  __shared__ f32x4 racc[2][64];
  int tid = threadIdx.x, lane = tid & 63, wid = tid >> 6;
  int sub = wid >> 1;  // tile slot in block
  int kh = wid & 1;    // k-half
  int nt = blockIdx.x * 2 + sub;
  int lv = (nt < 1024) ? 0 : ((nt < 1536) ? 1 : 2);
  int ntl = nt - ((lv == 0) ? 0 : ((lv == 1) ? 1024 : 1536));
  int tsh = 11 - lv;
  int T = 1 << tsh;
  const short* xp = (const short*)xT + ((lv == 0) ? 0 : ((lv == 1) ? 8388608 : 12582912));
  float* oc = offc + ((lv == 0) ? 0 : ((lv == 1) ? 49152 : 73728));
  int n = (ntl << 4) + (lane & 15);
  int b = n >> tsh;
  int t = n & (T - 1);
  const short* hip_ = (const short*)oHi + lane * 8;
  const short* lop_ = (const short*)oLo + lane * 8;
  int co = (lane >> 4) << 3;
  f32x4 acc = {};
  int kt0 = kh * 24;
  for (int kk = 0; kk < 24; ++kk) {
    int kt = kt0 + kk;
    int j = kt >> 4;
    int c0 = ((kt & 15) << 5) + co;
    int row = t + j - 1;
    bf16x8 bv = {};
    if ((unsigned)row < (unsigned)T)
      bv = *(const bf16x8*)(xp + (((size_t)(b << tsh) + row) << 9) + c0);
    bf16x8 ah = *(const bf16x8*)(hip_ + ((size_t)kt << 9));
    bf16x8 al = *(const bf16x8*)(lop_ + ((size_t)kt << 9));
    acc = __builtin_amdgcn_mfma_f32_16x16x32_bf16(ah, bv, acc, 0, 0, 0);
    acc = __builtin_amdgcn_mfma_f32_16x16x32_bf16(al, bv, acc, 0, 0, 0);
  }
  if (kh) racc[sub][lane] = acc;
  __syncthreads();
  if (!kh) {
    f32x4 o = racc[sub][lane];
    acc += o;
    if ((lane >> 4) == 0) {
#pragma unroll
      for (int r = 0; r < 3; ++r) oc[((b * 3 + r) << tsh) + t] = acc[r];
    }
  }
}

// ---------- fused deform-GEMM from transposed x (r2 structure: best measured 82.3us) ----------
// grid (224, 2): x = 128-t strip (level-batched), y = m-half (256 rows). 4 waves m-split.
// Per phase (one kt, K=32): stage S(kt+1) 128tx32k via clamped lerp, 32 MFMA vs S(kt).
// Single raw barrier per phase; A-frag dbuf prefetch; counted vmcnt spans barrier.
template <bool LAYER2, bool OUT_BF16>
__global__ __launch_bounds__(256, 2) void dgemm_kernel(
    const __hip_bfloat16* __restrict__ xT, const __hip_bfloat16* __restrict__ Wf,
    const float* __restrict__ off0, const float* __restrict__ off1,
    const float* __restrict__ off2, const float* __restrict__ P1,
    const float* __restrict__ offc2, const float* __restrict__ ob0v,
    const float* __restrict__ ob1v, const float* __restrict__ bias,
    const float* __restrict__ mk0, const float* __restrict__ mk1, const float* __restrict__ mk2,
    void* __restrict__ o0, void* __restrict__ o1, void* __restrict__ o2) {
  __shared__ short sS[2][4096];
  __shared__ int s_q[3][128];
  __shared__ float s_w0[3][128];
  __shared__ float s_w1[3][128];
  int tid = threadIdx.x, lane = tid & 63, wid = tid >> 6;
  int bx = blockIdx.x;
  int lv = (bx < 128) ? 0 : ((bx < 192) ? 1 : 2);
  int lbx = bx - ((lv == 0) ? 0 : ((lv == 1) ? 128 : 192));
  int tsh = 11 - lv;
  int T = 1 << tsh;
  const short* xp = (const short*)xT + ((lv == 0) ? 0 : ((lv == 1) ? 8388608 : 12582912));
  const float* offin = (lv == 0) ? off0 : ((lv == 1) ? off1 : off2);
  const float* P1l = P1 + ((lv == 0) ? 0 : ((lv == 1) ? 196608 : 294912));
  const float* oc2 = offc2 + ((lv == 0) ? 0 : ((lv == 1) ? 49152 : 73728));
  const float* mask = (lv == 0) ? mk0 : ((lv == 1) ? mk1 : mk2);
  void* outp = (lv == 0) ? o0 : ((lv == 1) ? o1 : o2);
  int nchunk = T >> 7;
  int b = lbx >> (tsh - 7);
  int tb = (lbx & (nchunk - 1)) << 7;
  int mhalf = blockIdx.y;

  // per-(tap,t) sample params: clamped rows + zeroable weights
  for (int idx = tid; idx < 384; idx += 256) {
    int k = idx >> 7, tl = idx & 127, t = tb + tl;
    int oi = ((b * 3 + k) << tsh) + t;
    int PT = 24 << tsh;
    float o = offin[oi] + ob0v[k];
    o += P1l[oi] + P1l[PT + oi] + P1l[2 * PT + oi] + P1l[3 * PT + oi];
    if (LAYER2) o += ob1v[k] + oc2[oi];
    float pos = (float)(t + k - 1) + o;
    float pf = floorf(pos);
    float fr = pos - pf;
    int q0 = (int)pf;
    int q1 = q0 + 1;
    bool ok0 = (unsigned)q0 < (unsigned)T;
    bool ok1 = (unsigned)q1 < (unsigned)T;
    int q0c = min(max(q0, 0), T - 1);
    int q1c = min(max(q1, 0), T - 1);
    s_q[k][tl] = (q0c & 0xffff) | (q1c << 16);
    s_w0[k][tl] = ok0 ? (1.f - fr) : 0.f;
    s_w1[k][tl] = ok1 ? fr : 0.f;
  }
  __syncthreads();

  // hoist params: (k3, half) -> rows + weights
  int q0r[3][2], q1r[3][2];
  float w0r[3][2], w1r[3][2];
#pragma unroll
  for (int k3 = 0; k3 < 3; ++k3)
#pragma unroll
    for (int h = 0; h < 2; ++h) {
      int tl = h * 64 + wid * 16 + (lane & 15);
      int qp = s_q[k3][tl];
      q0r[k3][h] = qp & 0xffff;
      q1r[k3][h] = (qp >> 16) & 0xffff;
      w0r[k3][h] = s_w0[k3][tl];
      w1r[k3][h] = s_w1[k3][tl];
    }
  // active staging params (k3 = 0)
  int asq0[2] = {q0r[0][0], q0r[0][1]}, asq1[2] = {q1r[0][0], q1r[0][1]};
  float aw0[2] = {w0r[0][0], w0r[0][1]}, aw1[2] = {w1r[0][0], w1r[0][1]};

  f32x4 acc[4][8] = {};
  const short* wfp = (const short*)Wf + (size_t)(mhalf * 16 + wid * 4) * 48 * 512 + lane * 8;
  unsigned co = (unsigned)((lane >> 4) << 3);
  const short* xrow = xp + (((size_t)(b << tsh)) << 9);
  short* smy0 = &sS[0][0] + ((wid << 9) + lane * 8);       // chunks wid and wid+4
  const short* smrd = &sS[0][0] + lane * 8;

  bf16x8 A[2][4];
  // ---- prologue: stage S(0) into buf0, load A[0] = aw(0) ----
  {
    bf16x8 L0[2], L1[2];
#pragma unroll
    for (int h = 0; h < 2; ++h) {
      L0[h] = *(const bf16x8*)(xrow + (((unsigned)asq0[h] << 9) + co));
      L1[h] = *(const bf16x8*)(xrow + (((unsigned)asq1[h] << 9) + co));
    }
#pragma unroll
    for (int i = 0; i < 4; ++i) A[0][i] = *(const bf16x8*)(wfp + ((size_t)(i * 48) << 9));
#pragma unroll
    for (int h = 0; h < 2; ++h) {
      bf16x8 ov;
#pragma unroll
      for (int j = 0; j < 8; ++j)
        ov[j] = f2b(b2f(L0[h][j]) * aw0[h] + b2f(L1[h][j]) * aw1[h]);
      *(bf16x8*)(smy0 + (h << 11)) = ov;
    }
    asm volatile("s_waitcnt lgkmcnt(0)" ::: "memory");
    __builtin_amdgcn_s_barrier();
    asm volatile("" ::: "memory");
  }

#pragma unroll 2
  for (int kt = 0; kt < 48; ++kt) {
    int cur = kt & 1;
    // switch staging params at tap boundaries (staging targets kt+1)
    if (kt == 15) {
#pragma unroll
      for (int h = 0; h < 2; ++h) {
        asq0[h] = q0r[1][h]; asq1[h] = q1r[1][h];
        aw0[h] = w0r[1][h];  aw1[h] = w1r[1][h];
      }
    } else if (kt == 31) {
#pragma unroll
      for (int h = 0; h < 2; ++h) {
        asq0[h] = q0r[2][h]; asq1[h] = q1r[2][h];
        aw0[h] = w0r[2][h];  aw1[h] = w1r[2][h];
      }
    }
    // issue gather loads for S(kt+1) and A-frags for kt+1
    bf16x8 L0[2], L1[2];
    if (kt < 47) {
      unsigned colo = ((unsigned)((kt + 1) & 15) << 5) + co;
#pragma unroll
      for (int h = 0; h < 2; ++h) {
        L0[h] = *(const bf16x8*)(xrow + (((unsigned)asq0[h] << 9) + colo));
        L1[h] = *(const bf16x8*)(xrow + (((unsigned)asq1[h] << 9) + colo));
      }
#pragma unroll
      for (int i = 0; i < 4; ++i)
        A[cur ^ 1][i] = *(const bf16x8*)(wfp + ((size_t)(i * 48 + kt + 1) << 9));
    }
    // MFMA on S(kt) from buf[cur]
    bf16x8 bv[8];
    const short* sb = smrd + (cur << 12);
#pragma unroll
    for (int jj = 0; jj < 8; ++jj) bv[jj] = *(const bf16x8*)(sb + (jj << 9));
    __builtin_amdgcn_s_setprio(1);
#pragma unroll
    for (int i = 0; i < 4; ++i)
#pragma unroll
      for (int jj = 0; jj < 8; ++jj)
        acc[i][jj] = __builtin_amdgcn_mfma_f32_16x16x32_bf16(A[cur][i], bv[jj], acc[i][jj], 0, 0, 0);
    __builtin_amdgcn_s_setprio(0);
    // lerp + stage S(kt+1) into buf[cur^1]
    if (kt < 47) {
      short* smw = smy0 + ((cur ^ 1) << 12);
#pragma unroll
      for (int h = 0; h < 2; ++h) {
        bf16x8 ov;
#pragma unroll
        for (int j = 0; j < 8; ++j)
          ov[j] = f2b(b2f(L0[h][j]) * aw0[h] + b2f(L1[h][j]) * aw1[h]);
        *(bf16x8*)(smw + (h << 11)) = ov;
      }
    }
    asm volatile("s_waitcnt lgkmcnt(0)" ::: "memory");
    __builtin_amdgcn_s_barrier();
    asm volatile("" ::: "memory");
  }

  // epilogue: D row = (lane>>4)*4 + reg (m), col = lane&15 (t); 8 t-tiles
  int lrow = lane & 15, lq = lane >> 4;
  int mbase = mhalf * 256 + wid * 64;
  float bvals[4][4];
#pragma unroll
  for (int i = 0; i < 4; ++i)
#pragma unroll
    for (int r = 0; r < 4; ++r) bvals[i][r] = bias[mbase + i * 16 + lq * 4 + r];
#pragma unroll
  for (int j = 0; j < 8; ++j) {
    int col = j * 16 + lrow;
    int t = tb + col;
    float mk = mask[(b << tsh) + t];
    if (OUT_BF16) {
      short* orow = (short*)outp + (((size_t)(b << tsh) + t) << 9);
#pragma unroll
      for (int i = 0; i < 4; ++i) {
        bf16x4 pv;
#pragma unroll
        for (int r = 0; r < 4; ++r)
          pv[r] = f2b(fmaxf(acc[i][j][r] + bvals[i][r], 0.f) * mk);
        *(bf16x4*)(orow + mbase + i * 16 + lq * 4) = pv;
      }
    } else {
#pragma unroll
      for (int i = 0; i < 4; ++i) {
        int m = mbase + i * 16 + lq * 4;
#pragma unroll
        for (int r = 0; r < 4; ++r) {
          float v = fmaxf(acc[i][j][r] + bvals[i][r], 0.f) * mk;
          ((float*)outp)[(((size_t)(b * 512 + m + r)) << tsh) + t] = v;
        }
      }
    }
  }
}

// ---------- launch ----------
extern "C" void kernel_launch(void* const* d_in, const int* in_sizes, int n_in, void* d_out,
                              int out_size, void* d_ws, size_t ws_size, hipStream_t stream) {
  const float* feats[3] = {(const float*)d_in[0], (const float*)d_in[3], (const float*)d_in[6]};
  const float* maskp[3] = {(const float*)d_in[1], (const float*)d_in[4], (const float*)d_in[7]};
  const float* offs[3] = {(const float*)d_in[2], (const float*)d_in[5], (const float*)d_in[8]};
  const float* w[2] = {(const float*)d_in[9], (const float*)d_in[13]};
  const float* bias[2] = {(const float*)d_in[10], (const float*)d_in[14]};
  const float* ow[2] = {(const float*)d_in[11], (const float*)d_in[15]};
  const float* ob[2] = {(const float*)d_in[12], (const float*)d_in[16]};

  const size_t YOFF[3] = {0, 8388608, 12582912};
  const size_t MOFF = 14680064;

  uint8_t* ws = (uint8_t*)d_ws;
  __hip_bfloat16* Wf0 = (__hip_bfloat16*)ws;                 // 1,572,864 B
  __hip_bfloat16* Wf1 = (__hip_bfloat16*)(ws + 1572864);     // 1,572,864 B
  __hip_bfloat16* owF1hi = (__hip_bfloat16*)(ws + 3145728);  // 49,152 B
  __hip_bfloat16* owF1lo = (__hip_bfloat16*)(ws + 3194880);  // 49,152 B
  float* P1 = (float*)(ws + 3244032);                        // 1,376,256 B
  float* offc2 = (float*)(ws + 4620288);                     // 344,064 B
  __hip_bfloat16* fT = (__hip_bfloat16*)(ws + 8388608);      // 29,360,128 B
  __hip_bfloat16* x1T = (__hip_bfloat16*)(ws + 37748736);    // 29,360,128 B (end 67,108,864)

  float* outf = (float*)d_out;

  // fused setup + transpose + layer-1 offset conv (reads feats once)
  prep_kernel<<<dim3(448, 4), 256, 0, stream>>>(
      feats[0], feats[1], feats[2], ow[0], P1, fT, w[0], w[1], Wf0, Wf1, ow[1], owF1hi, owF1lo,
      maskp[0], maskp[1], maskp[2], outf + MOFF);

  // layer 1
  dgemm_kernel<false, true><<<dim3(224, 2), 256, 0, stream>>>(
      fT, Wf0, offs[0], offs[1], offs[2], P1, offc2, ob[0], ob[1], bias[0],
      maskp[0], maskp[1], maskp[2], (void*)x1T, (void*)(x1T + YOFF[1]), (void*)(x1T + YOFF[2]));

  // layer 2
  offconv2_kernel<<<896, 256, 0, stream>>>(x1T, owF1hi, owF1lo, offc2);
  dgemm_kernel<true, false><<<dim3(224, 2), 256, 0, stream>>>(
      x1T, Wf1, offs[0], offs[1], offs[2], P1, offc2, ob[0], ob[1], bias[1],
      maskp[0], maskp[1], maskp[2], (void*)(outf + YOFF[0]), (void*)(outf + YOFF[1]),
      (void*)(outf + YOFF[2]));
}